// Round 1
// baseline (103.686 us; speedup 1.0000x reference)
//
#include <hip/hip_runtime.h>
#include <hip/hip_cooperative_groups.h>

namespace cg = cooperative_groups;

// RadialNetwork2d: out[b,a] = NORM * sum_k exp(-2*||p_b - c_k||^2) * W[k,a] + bias[a]
//
// R8 -> R9: R8's two tiny kernels (table build ~3us, bilinear eval ~2us) cost
// ~22-27us of launch + full-drain overhead on top of ~5us of real work (the
// other ~41us of dur_us is the harness's 256MiB workspace poison fill, 82% HBM,
// not controllable). Fuse into ONE cooperative kernel:
//   - grid 256x256 = 65536 threads = BATCH exactly, 1 block/CU -> co-residency
//     guaranteed, grid.sync() safe (sanctioned harness path for grid-wide sync).
//   - each thread prefetches its pos[r] BEFORE the table build (0.5MB read
//     hidden under stage-A compute).
//   - bias folded into the table (bilinear weights sum to 1 -> exact).
// Table math unchanged from R8: T on 321x321 grid (h=10/320), per y-row
// H_i[a]=NORM*sum_j fy_j W[i,j,a] in LDS, T[yk][xk]=sum_i fx_i*H_i; interp
// err ~1e-4 << tolerance.

#define NC   40
#define NX   320            // grid segments per axis; h = 10/320
#define NXP  (NX + 1)       // grid points per axis
#define GRID 256
#define BLK  256

typedef float v2f __attribute__((ext_vector_type(2)));

__global__ __launch_bounds__(BLK, 1) void fused_radial(
    const float2* __restrict__ pos,       // [B]
    const float*  __restrict__ centers,   // [1600*2]
    const float4* __restrict__ W,         // [1600]
    const float*  __restrict__ bias,      // [4]
    float4*       __restrict__ tab,       // [NXP*NXP] workspace
    float4*       __restrict__ out,       // [B]
    int batch)
{
    const int t = threadIdx.x;
    const int b = blockIdx.x;
    const int r = b * BLK + t;

    // ---- prefetch this thread's row input; overlaps with table build ----
    float2 p = make_float2(0.f, 0.f);
    if (r < batch) p = pos[r];

    const float b0 = bias[0], b1 = bias[1], b2 = bias[2], b3 = bias[3];

    __shared__ float Hs[NC * 4];          // H_i[a] for current yk (640 B)
    const float h = 10.0f / NX;

    // ---- stage A: build table rows, grid-strided over yk (blocks 0..64 do 2) ----
    for (int yk = b; yk < NXP; yk += GRID) {
        const float ykf = (float)yk * h;

        if (t < NC * 4) {
            const int i = t >> 2, a = t & 3;
            const float* Wf = (const float*)W;
            float acc = 0.f;
#pragma unroll 8
            for (int j = 0; j < NC; ++j) {
                const float dy = ykf - centers[2 * j + 1];   // yr[j], uniform
                const float fy = __expf(-2.0f * dy * dy);
                acc = fmaf(fy, Wf[(i * NC + j) * 4 + a], acc);
            }
            Hs[t] = acc * 0.6366197723675814f;               // NORM = 1/(2*pi*0.25)
        }
        __syncthreads();

        for (int xk = t; xk < NXP; xk += BLK) {
            const float xkf = (float)xk * h;
            v2f a01 = {b0, b1}, a23 = {b2, b3};              // bias folded in (exact)
#pragma unroll 8
            for (int i = 0; i < NC; ++i) {
                const float dx = xkf - centers[2 * (i * NC)]; // xr[i], uniform
                const float fx = __expf(-2.0f * dx * dx);
                const float4 hh = *(const float4*)&Hs[i * 4]; // LDS broadcast
                const v2f fv  = {fx, fx};
                const v2f h01 = {hh.x, hh.y};
                const v2f h23 = {hh.z, hh.w};
                a01 = __builtin_elementwise_fma(fv, h01, a01);
                a23 = __builtin_elementwise_fma(fv, h23, a23);
            }
            float4 o;
            o.x = a01.x; o.y = a01.y; o.z = a23.x; o.w = a23.y;
            tab[yk * NXP + xk] = o;                          // coalesced
        }
        __syncthreads();   // Hs reused next yk iteration
    }

    // ---- grid-wide barrier: table complete & visible device-wide ----
    cg::this_grid().sync();

    // ---- stage B: one bilinear lookup per thread ----
    if (r >= batch) return;

    float tx = p.x * ((float)NX / 10.0f);
    float ty = p.y * ((float)NX / 10.0f);
    int ix = (int)tx; ix = min(max(ix, 0), NX - 1);
    int iy = (int)ty; iy = min(max(iy, 0), NX - 1);
    const float fx = tx - (float)ix;
    const float fy = ty - (float)iy;

    const float4* row0 = tab + iy * NXP + ix;
    const float4* row1 = row0 + NXP;
    const float4 c00 = row0[0], c10 = row0[1];   // adjacent 16B pairs
    const float4 c01 = row1[0], c11 = row1[1];

    float4 top, bot, o;
    top.x = fmaf(fx, c10.x - c00.x, c00.x);
    top.y = fmaf(fx, c10.y - c00.y, c00.y);
    top.z = fmaf(fx, c10.z - c00.z, c00.z);
    top.w = fmaf(fx, c10.w - c00.w, c00.w);
    bot.x = fmaf(fx, c11.x - c01.x, c01.x);
    bot.y = fmaf(fx, c11.y - c01.y, c01.y);
    bot.z = fmaf(fx, c11.z - c01.z, c01.z);
    bot.w = fmaf(fx, c11.w - c01.w, c01.w);
    o.x = fmaf(fy, bot.x - top.x, top.x);        // bias already in table
    o.y = fmaf(fy, bot.y - top.y, top.y);
    o.z = fmaf(fy, bot.z - top.z, top.z);
    o.w = fmaf(fy, bot.w - top.w, top.w);
    out[r] = o;
}

extern "C" void kernel_launch(void* const* d_in, const int* in_sizes, int n_in,
                              void* d_out, int out_size, void* d_ws, size_t ws_size,
                              hipStream_t stream) {
    const float2* pos     = (const float2*)d_in[0];
    const float*  centers = (const float*) d_in[1];
    const float4* W       = (const float4*)d_in[2];
    const float*  bias    = (const float*) d_in[3];
    float4*       out     = (float4*)d_out;
    float4*       tab     = (float4*)d_ws;          // 321*321*16 B = 1.65 MB

    int batch = in_sizes[0] / 2;                    // 65536

    void* args[] = {(void*)&pos, (void*)&centers, (void*)&W, (void*)&bias,
                    (void*)&tab, (void*)&out, (void*)&batch};
    hipLaunchCooperativeKernel((void*)fused_radial, dim3(GRID), dim3(BLK),
                               args, 0, stream);
}

// Round 2
// 67.267 us; speedup vs baseline: 1.5414x; 1.5414x over previous
//
#include <hip/hip_runtime.h>

// RadialNetwork2d: out[b,a] = NORM * sum_k exp(-2*||p_b - c_k||^2) * W[k,a] + bias[a]
//
// R9 -> R10: REVERT the cooperative fusion (R9: 103.7us, +36us of cooperative
// launch machinery vs the plain two-kernel graph nodes). R8's 68us decomposes as
// ~41us harness 256MiB ws poison fill (82% HBM, its own roofline) + ~15-20us of
// tiny harness reset memsets + ~6us of actual kernels -> R8 was already at the
// harness floor. Restore R8 exactly, keeping R9's one real improvement: bias is
// folded into the table (bilinear weights sum to 1 -> exact), so stage B drops
// the bias loads + 4 adds.
//
// Table math: out is a smooth function T(x,y) of 2 scalars -> tabulate T on a
// 321x321 grid (h=10/320), bilinear-interp per row; interp err ~1e-4 << 4e-3.
// Stage A (321 blocks): per y-gridpoint H_i[a]=NORM*sum_j fy_j W[i,j,a] in LDS
// (160 dots of 40), then T[yk][xk]=sum_i fx_i(xk)*H_i + bias.
// Stage B: per row ONE bilinear lookup = 4 float4 gathers + ~25 VALU.

#define NC  40
#define NX  320           // grid segments per axis; h = 10/320
#define NXP (NX + 1)      // grid points per axis

typedef float v2f __attribute__((ext_vector_type(2)));

// ---------- Stage A: tab[yk*NXP + xk] = T(xk*h, yk*h) + bias ----------
__global__ __launch_bounds__(384) void build_table(
    const float*  __restrict__ centers,   // [1600*2]
    const float4* __restrict__ W,         // [1600]
    const float*  __restrict__ bias,      // [4]
    float4*       __restrict__ tab)       // [NXP*NXP]
{
    const int   yk  = blockIdx.x;         // 0..NX (321 blocks)
    const float h   = 10.0f / NX;
    const float ykf = (float)yk * h;

    __shared__ float Hs[NC * 4];          // H_i[a] for this yk (640 B)

    const int t = threadIdx.x;

    // phase 1: threads 0..159 each compute one H[i][a] = NORM * sum_j fy_j * W[i*40+j][a]
    if (t < NC * 4) {
        const int i = t >> 2, a = t & 3;
        const float* Wf = (const float*)W;
        float acc = 0.f;
#pragma unroll 8
        for (int j = 0; j < NC; ++j) {
            const float dy = ykf - centers[2 * j + 1];   // yr[j], uniform
            const float fy = __expf(-2.0f * dy * dy);
            acc = fmaf(fy, Wf[(i * NC + j) * 4 + a], acc);
        }
        Hs[t] = acc * 0.6366197723675814f;               // NORM = 1/(2*pi*0.25)
    }
    __syncthreads();

    // phase 2: threads 0..320 each compute one table entry T[yk][xk] (+bias)
    if (t < NXP) {
        const float xkf = (float)t * h;
        v2f a01 = {bias[0], bias[1]};                    // bias folded in (exact:
        v2f a23 = {bias[2], bias[3]};                    //  bilinear wts sum to 1)
#pragma unroll 8
        for (int i = 0; i < NC; ++i) {
            const float dx = xkf - centers[2 * (i * NC)];  // xr[i], uniform
            const float fx = __expf(-2.0f * dx * dx);
            const float4 hh = *(const float4*)&Hs[i * 4];  // LDS broadcast
            const v2f fv  = {fx, fx};
            const v2f h01 = {hh.x, hh.y};
            const v2f h23 = {hh.z, hh.w};
            a01 = __builtin_elementwise_fma(fv, h01, a01);
            a23 = __builtin_elementwise_fma(fv, h23, a23);
        }
        float4 o;
        o.x = a01.x; o.y = a01.y; o.z = a23.x; o.w = a23.y;
        tab[yk * NXP + t] = o;                             // coalesced
    }
}

// ---------- Stage B: out[r] = bilinear(tab; x,y) ----------
__global__ __launch_bounds__(256) void radial_eval(
    const float2* __restrict__ pos,       // [B]
    const float4* __restrict__ tab,       // [NXP*NXP]
    float4*       __restrict__ out,       // [B]
    int batch)
{
    const int r = blockIdx.x * 256 + threadIdx.x;
    if (r >= batch) return;
    const float2 p = pos[r];

    float tx = p.x * ((float)NX / 10.0f);
    float ty = p.y * ((float)NX / 10.0f);
    int ix = (int)tx; if (ix > NX - 1) ix = NX - 1; if (ix < 0) ix = 0;
    int iy = (int)ty; if (iy > NX - 1) iy = NX - 1; if (iy < 0) iy = 0;
    const float fx = tx - (float)ix;
    const float fy = ty - (float)iy;

    const float4* row0 = tab + iy * NXP + ix;
    const float4* row1 = row0 + NXP;
    const float4 c00 = row0[0], c10 = row0[1];   // adjacent 16B pairs
    const float4 c01 = row1[0], c11 = row1[1];

    float4 top, bot, o;
    top.x = fmaf(fx, c10.x - c00.x, c00.x);
    top.y = fmaf(fx, c10.y - c00.y, c00.y);
    top.z = fmaf(fx, c10.z - c00.z, c00.z);
    top.w = fmaf(fx, c10.w - c00.w, c00.w);
    bot.x = fmaf(fx, c11.x - c01.x, c01.x);
    bot.y = fmaf(fx, c11.y - c01.y, c01.y);
    bot.z = fmaf(fx, c11.z - c01.z, c01.z);
    bot.w = fmaf(fx, c11.w - c01.w, c01.w);
    o.x = fmaf(fy, bot.x - top.x, top.x);        // bias already in table
    o.y = fmaf(fy, bot.y - top.y, top.y);
    o.z = fmaf(fy, bot.z - top.z, top.z);
    o.w = fmaf(fy, bot.w - top.w, top.w);
    out[r] = o;
}

extern "C" void kernel_launch(void* const* d_in, const int* in_sizes, int n_in,
                              void* d_out, int out_size, void* d_ws, size_t ws_size,
                              hipStream_t stream) {
    const float2* pos     = (const float2*)d_in[0];
    const float*  centers = (const float*) d_in[1];
    const float4* W       = (const float4*)d_in[2];
    const float*  bias    = (const float*) d_in[3];
    float4*       out     = (float4*)d_out;
    float4*       tab     = (float4*)d_ws;          // 321*321*16 B = 1.65 MB

    const int batch = in_sizes[0] / 2;              // 65536

    build_table<<<NXP, 384, 0, stream>>>(centers, W, bias, tab);

    const int gridB = (batch + 255) / 256;
    radial_eval<<<gridB, 256, 0, stream>>>(pos, tab, out, batch);
}